// Round 4
// baseline (146.709 us; speedup 1.0000x reference)
//
#include <hip/hip_runtime.h>

#define LAMBDA_COORD 5.0f
#define LAMBDA_NOOBJ 0.5f

constexpr int Bn = 64;       // batch
constexpr int An = 10647;    // anchors
constexpr int Cn = 9;        // classes
constexpr int Gn = 50;       // gt boxes
constexpr int PRED_ROW = 5 + Cn;        // 14 floats per anchor row
constexpr int S  = 16;                  // anchor splits
constexpr int AC = (An + S - 1) / S;    // 666 anchors per split
constexpr int ACP = ((AC + 63) / 64) * 64;  // 704, padded (branch-free main loop)
constexpr int GTW = 13;                 // GTs per wave (13+13+13+11 = 50)

// ws layout:
//   partials : Bn*Gn*S float2 (score, idx-as-bits)  = 409600 B
//   bcepart  : Bn*S floats                           = 4096 B

// __launch_bounds__(256, 4): 4 waves/EU min -> VGPR cap 512/4 = 128.
// The 13-GT tile needs ~120 live VGPRs; at the default cap (64) the compiler
// spills the bn/bd/bidx/g* arrays to scratch inside the 13-way inner loop.
__global__ __launch_bounds__(256, 4) void yolo_k1(
    const float* __restrict__ pred,     // [B, A, 14]
    const float* __restrict__ bboxes,   // [B, G, 4]
    float2* __restrict__ partials,      // [B, G, S]
    float* __restrict__ bcepart)        // [B, S]
{
    const int s = blockIdx.x;
    const int b = blockIdx.y;
    const int a0 = s * AC;
    const int n  = min(AC, An - a0);    // 666 (657 for last split)

    __shared__ float4 sbox[ACP];  // x1,y1,x2,y2
    __shared__ float  sap[ACP];   // area_p
    __shared__ float  sred[4];

    const int tid  = threadIdx.x;
    const int wave = tid >> 6;
    const int lane = tid & 63;

    // ---- stage anchors into LDS (padded), accumulate partial bce0 sum ----
    const float* prow = pred + (size_t)b * An * PRED_ROW;
    float bce = 0.0f;
    for (int i = tid; i < ACP; i += 256) {
        if (i < n) {
            const float* p = prow + (size_t)(a0 + i) * PRED_ROW;
            const float2* p2 = (const float2*)p;      // 56*a is 8B-aligned
            float2 v0 = p2[0], v1 = p2[1];
            float conf = p[4];
            float hw = 0.5f * v1.x, hh = 0.5f * v1.y;
            float x1 = v0.x - hw, x2 = v0.x + hw;
            float y1 = v0.y - hh, y2 = v0.y + hh;
            sbox[i] = make_float4(x1, y1, x2, y2);
            sap[i]  = (x2 - x1) * (y2 - y1);
            bce -= fmaxf(__logf(1.0f - conf), -100.0f);   // bce0
        } else {
            // degenerate pad: intersection always 0, never selected (strict >)
            sbox[i] = make_float4(1e30f, 1e30f, 1e30f, 1e30f);
            sap[i]  = 0.0f;
        }
    }
    #pragma unroll
    for (int off = 32; off >= 1; off >>= 1) bce += __shfl_xor(bce, off, 64);
    if (lane == 0) sred[wave] = bce;

    // ---- per-wave GT tile into registers ----
    const int g0 = wave * GTW;
    const int ng = min(GTW, Gn - g0);   // 13,13,13,11

    float gx1[GTW], gy1[GTW], gx2[GTW], gy2[GTW], gc1[GTW];
    const float* bb = bboxes + (size_t)b * Gn * 4;
    #pragma unroll
    for (int j = 0; j < GTW; ++j) {
        int g = (j < ng) ? (g0 + j) : g0;    // pad tail with duplicate GT
        float b0 = bb[g * 4 + 0], b1 = bb[g * 4 + 1];
        float b2 = bb[g * 4 + 2], b3 = bb[g * 4 + 3];
        float gcx = 0.5f * (b0 + b2), gcy = 0.5f * (b1 + b3);
        float gw = b2 - b0, gh = b3 - b1;
        gx1[j] = gcx - gw * 0.5f; gx2[j] = gcx + gw * 0.5f;
        gy1[j] = gcy - gh * 0.5f; gy2[j] = gcy + gh * 0.5f;
        gc1[j] = (gx2[j] - gx1[j]) * (gy2[j] - gy1[j]) + 1e-16f;  // area_g + eps
    }

    float bn[GTW], bd[GTW];
    int   bidx[GTW];
    #pragma unroll
    for (int j = 0; j < GTW; ++j) { bn[j] = 0.0f; bd[j] = 1.0f; bidx[j] = 0; }

    __syncthreads();
    if (tid == 0) bcepart[b * S + s] = sred[0] + sred[1] + sred[2] + sred[3];

    // ---- main scan: branch-free, 13 IoUs per anchor read ----
    for (int base = 0; base < ACP; base += 64) {
        int i = base + lane;
        float4 pb = sbox[i];
        float  ap = sap[i];
        int   idx = a0 + i;
        #pragma unroll
        for (int j = 0; j < GTW; ++j) {
            float iw = fminf(pb.z, gx2[j]) - fmaxf(pb.x, gx1[j]);
            float ih = fminf(pb.w, gy2[j]) - fmaxf(pb.y, gy1[j]);
            iw = fmaxf(iw, 0.0f);
            ih = fmaxf(ih, 0.0f);
            float inter = iw * ih;
            float apc   = ap + gc1[j];
            // argmax of inter/(ap+ag-inter) == argmax of inter/(ap+ag):
            // r -> r/(1+r) monotone; compare fractions by cross-multiply.
            bool take = inter * bd[j] > bn[j] * apc;   // strict >: first max wins
            bn[j]   = take ? inter : bn[j];
            bd[j]   = take ? apc   : bd[j];
            bidx[j] = take ? idx   : bidx[j];
        }
    }

    // ---- cross-lane argmax per GT, write partial ----
    #pragma unroll
    for (int j = 0; j < GTW; ++j) {
        if (j < ng) {
            float score = bn[j] * __builtin_amdgcn_rcpf(bd[j]);  // monotone in iou
            int   idx   = bidx[j];
            #pragma unroll
            for (int off = 1; off < 64; off <<= 1) {
                float os = __shfl_xor(score, off, 64);
                int   oi = __shfl_xor(idx, off, 64);
                if (os > score) { score = os; idx = oi; }
            }
            if (lane == 0)
                partials[((size_t)b * Gn + g0 + j) * S + s] =
                    make_float2(score, __int_as_float(idx));
        }
    }
}

// k2+k3 fused: one block, 16 waves; wave w handles images w, w+16, w+32, w+48.
// Kernel boundary after k1 provides all cross-block coherence (no fences).
__global__ __launch_bounds__(1024) void yolo_k23(
    const float* __restrict__ pred,
    const float* __restrict__ bboxes,
    const int*  __restrict__ classes,   // [B, G]
    const float2* __restrict__ partials,
    const float* __restrict__ bcepart,
    float* __restrict__ out)            // [1]
{
    __shared__ float simg[Bn];

    const int tid  = threadIdx.x;
    const int wave = tid >> 6;
    const int lane = tid & 63;

    for (int b = wave; b < Bn; b += 16) {
        const int g = lane;

        float tot0 = 0.0f;
        #pragma unroll
        for (int ss = 0; ss < S; ++ss) tot0 += bcepart[b * S + ss];  // broadcast

        float per_gt = 0.0f;
        int   validf = 0;
        if (g < Gn) {
            int cls = classes[b * Gn + g];
            validf = (cls != -1) ? 1 : 0;

            // fold the S partial argmax candidates
            const float2* pp = partials + ((size_t)b * Gn + g) * S;
            float best = -1.0f;
            int   bi = 0;
            #pragma unroll
            for (int ss = 0; ss < S; ++ss) {
                float2 c = pp[ss];
                if (c.x > best) { best = c.x; bi = __float_as_int(c.y); }
            }

            const float* p = pred + ((size_t)b * An + bi) * PRED_ROW;
            float pcx = p[0], pcy = p[1], pw = p[2], ph = p[3], conf = p[4];

            const float* bbg = bboxes + ((size_t)b * Gn + g) * 4;
            float b0 = bbg[0], b1 = bbg[1], b2 = bbg[2], b3 = bbg[3];
            float gcx = 0.5f * (b0 + b2), gcy = 0.5f * (b1 + b3);
            float gw = b2 - b0, gh = b3 - b1;

            float dx = pcx - gcx, dy = pcy - gcy, dw = pw - gw, dh = ph - gh;
            float coord = LAMBDA_COORD * (dx * dx + dy * dy + dw * dw + dh * dh);

            float conf_obj = -fmaxf(__logf(conf), -100.0f);

            float clsl = 0.0f;
            #pragma unroll
            for (int c = 0; c < Cn; ++c) {
                float pc = p[5 + c];
                float lp = fmaxf(__logf(pc), -100.0f);
                float ln = fmaxf(__logf(1.0f - pc), -100.0f);
                clsl -= (c == cls) ? lp : ln;
            }

            float bce0b = -fmaxf(__logf(1.0f - conf), -100.0f);
            float noobj = LAMBDA_NOOBJ * (tot0 - bce0b);

            per_gt = coord + conf_obj + clsl + noobj;
            if (!validf) per_gt = 0.0f;
        }

        float sum = per_gt;
        int   anyv = validf;
        #pragma unroll
        for (int off = 1; off < 64; off <<= 1) {
            sum  += __shfl_xor(sum, off, 64);
            anyv |= __shfl_xor(anyv, off, 64);
        }
        if (lane == 0) simg[b] = anyv ? sum : (LAMBDA_NOOBJ * tot0);
    }

    __syncthreads();
    if (wave == 0) {
        float v = simg[lane];      // Bn == 64 == one wave
        #pragma unroll
        for (int off = 1; off < 64; off <<= 1) v += __shfl_xor(v, off, 64);
        if (lane == 0) out[0] = v * (1.0f / (float)Bn);
    }
}

extern "C" void kernel_launch(void* const* d_in, const int* in_sizes, int n_in,
                              void* d_out, int out_size, void* d_ws, size_t ws_size,
                              hipStream_t stream) {
    const float* pred    = (const float*)d_in[0];
    const float* bboxes  = (const float*)d_in[1];
    const int*   classes = (const int*)d_in[2];
    float* out = (float*)d_out;

    char* ws = (char*)d_ws;
    float2* partials = (float2*)ws;
    float*  bcepart  = (float*)(ws + (size_t)Bn * Gn * S * sizeof(float2));

    yolo_k1<<<dim3(S, Bn), 256, 0, stream>>>(pred, bboxes, partials, bcepart);
    yolo_k23<<<1, 1024, 0, stream>>>(pred, bboxes, classes, partials, bcepart, out);
}

// Round 5
// 107.390 us; speedup vs baseline: 1.3661x; 1.3661x over previous
//
#include <hip/hip_runtime.h>

#define LAMBDA_COORD 5.0f
#define LAMBDA_NOOBJ 0.5f

constexpr int Bn = 64;       // batch
constexpr int An = 10647;    // anchors
constexpr int Cn = 9;        // classes
constexpr int Gn = 50;       // gt boxes
constexpr int PRED_ROW = 5 + Cn;        // 14 floats per anchor row
constexpr int S  = 16;                  // anchor splits
constexpr int AC = (An + S - 1) / S;    // 666 anchors per split
constexpr int ACP = ((AC + 63) / 64) * 64;  // 704, padded (branch-free main loop)
constexpr int GTW = 13;                 // GTs per wave (13+13+13+11 = 50)

// ws layout:
//   partials : Bn*Gn*S float2 (score, idx-as-bits)  = 409600 B
//   bcepart  : Bn*S floats                           = 4096 B
//   per_img  : Bn floats                             = 256 B

// __launch_bounds__(256, 4): VGPR cap 512/4 = 128 — fits the ~120-reg live
// set (13-GT tile + accumulators); default cap (64) spills to scratch.
__global__ __launch_bounds__(256, 4) void yolo_k1(
    const float* __restrict__ pred,     // [B, A, 14]
    const float* __restrict__ bboxes,   // [B, G, 4]
    float2* __restrict__ partials,      // [B, G, S]
    float* __restrict__ bcepart)        // [B, S]
{
    const int s = blockIdx.x;
    const int b = blockIdx.y;
    const int a0 = s * AC;
    const int n  = min(AC, An - a0);    // 666 (657 for last split)

    __shared__ float4 sbox[ACP];  // x1,y1,x2,y2
    __shared__ float  sap[ACP];   // area_p
    __shared__ float  sred[4];

    const int tid  = threadIdx.x;
    const int wave = tid >> 6;
    const int lane = tid & 63;

    // ---- stage anchors into LDS (padded), accumulate partial bce0 sum ----
    const float* prow = pred + (size_t)b * An * PRED_ROW;
    float bce = 0.0f;
    for (int i = tid; i < ACP; i += 256) {
        if (i < n) {
            const float* p = prow + (size_t)(a0 + i) * PRED_ROW;
            const float2* p2 = (const float2*)p;      // 56*a is 8B-aligned
            float2 v0 = p2[0], v1 = p2[1];
            float conf = p[4];
            float hw = 0.5f * v1.x, hh = 0.5f * v1.y;
            float x1 = v0.x - hw, x2 = v0.x + hw;
            float y1 = v0.y - hh, y2 = v0.y + hh;
            sbox[i] = make_float4(x1, y1, x2, y2);
            sap[i]  = (x2 - x1) * (y2 - y1);
            bce -= fmaxf(__logf(1.0f - conf), -100.0f);   // bce0
        } else {
            // degenerate pad: intersection always 0, never selected (strict >)
            sbox[i] = make_float4(1e30f, 1e30f, 1e30f, 1e30f);
            sap[i]  = 0.0f;
        }
    }
    #pragma unroll
    for (int off = 32; off >= 1; off >>= 1) bce += __shfl_xor(bce, off, 64);
    if (lane == 0) sred[wave] = bce;

    // ---- per-wave GT tile into registers ----
    const int g0 = wave * GTW;
    const int ng = min(GTW, Gn - g0);   // 13,13,13,11

    float gx1[GTW], gy1[GTW], gx2[GTW], gy2[GTW], gc1[GTW];
    const float* bb = bboxes + (size_t)b * Gn * 4;
    #pragma unroll
    for (int j = 0; j < GTW; ++j) {
        int g = (j < ng) ? (g0 + j) : g0;    // pad tail with duplicate GT
        float b0 = bb[g * 4 + 0], b1 = bb[g * 4 + 1];
        float b2 = bb[g * 4 + 2], b3 = bb[g * 4 + 3];
        float gcx = 0.5f * (b0 + b2), gcy = 0.5f * (b1 + b3);
        float gw = b2 - b0, gh = b3 - b1;
        gx1[j] = gcx - gw * 0.5f; gx2[j] = gcx + gw * 0.5f;
        gy1[j] = gcy - gh * 0.5f; gy2[j] = gcy + gh * 0.5f;
        gc1[j] = (gx2[j] - gx1[j]) * (gy2[j] - gy1[j]) + 1e-16f;  // area_g + eps
    }

    float bn[GTW], bd[GTW];
    int   bidx[GTW];
    #pragma unroll
    for (int j = 0; j < GTW; ++j) { bn[j] = 0.0f; bd[j] = 1.0f; bidx[j] = 0; }

    __syncthreads();
    if (tid == 0) bcepart[b * S + s] = sred[0] + sred[1] + sred[2] + sred[3];

    // ---- main scan: branch-free, 13 IoUs per anchor read ----
    for (int base = 0; base < ACP; base += 64) {
        int i = base + lane;
        float4 pb = sbox[i];
        float  ap = sap[i];
        int   idx = a0 + i;
        #pragma unroll
        for (int j = 0; j < GTW; ++j) {
            float iw = fminf(pb.z, gx2[j]) - fmaxf(pb.x, gx1[j]);
            float ih = fminf(pb.w, gy2[j]) - fmaxf(pb.y, gy1[j]);
            iw = fmaxf(iw, 0.0f);
            ih = fmaxf(ih, 0.0f);
            float inter = iw * ih;
            float apc   = ap + gc1[j];
            // argmax of inter/(ap+ag-inter) == argmax of inter/(ap+ag):
            // r -> r/(1+r) monotone; compare fractions by cross-multiply.
            bool take = inter * bd[j] > bn[j] * apc;   // strict >: first max wins
            bn[j]   = take ? inter : bn[j];
            bd[j]   = take ? apc   : bd[j];
            bidx[j] = take ? idx   : bidx[j];
        }
    }

    // ---- cross-lane argmax per GT, write partial ----
    #pragma unroll
    for (int j = 0; j < GTW; ++j) {
        if (j < ng) {
            float score = bn[j] * __builtin_amdgcn_rcpf(bd[j]);  // monotone in iou
            int   idx   = bidx[j];
            #pragma unroll
            for (int off = 1; off < 64; off <<= 1) {
                float os = __shfl_xor(score, off, 64);
                int   oi = __shfl_xor(idx, off, 64);
                if (os > score) { score = os; idx = oi; }
            }
            if (lane == 0)
                partials[((size_t)b * Gn + g0 + j) * S + s] =
                    make_float2(score, __int_as_float(idx));
        }
    }
}

// k2: one block per image, 64 lanes; lane g owns GT g. __launch_bounds__(64,1)
// removes the VGPR cap so the 16-partial fold + pred row issue as parallel
// loads (round 4's single-block variant had VGPR=28 -> serial latency chain).
__global__ __launch_bounds__(64, 1) void yolo_k2(
    const float* __restrict__ pred,
    const float* __restrict__ bboxes,
    const int*  __restrict__ classes,   // [B, G]
    const float2* __restrict__ partials,
    const float* __restrict__ bcepart,
    float* __restrict__ per_img)        // [B]
{
    const int b = blockIdx.x;
    const int g = threadIdx.x;

    // issue all independent loads up front
    int cls = (g < Gn) ? classes[b * Gn + g] : -1;

    float tot0 = 0.0f;
    #pragma unroll
    for (int s = 0; s < S; ++s) tot0 += bcepart[b * S + s];  // broadcast loads

    float per_gt = 0.0f;
    int   validf = 0;
    if (g < Gn) {
        validf = (cls != -1) ? 1 : 0;

        // fold the S partial argmax candidates (scores comparable across splits)
        const float2* pp = partials + ((size_t)b * Gn + g) * S;
        float2 c[S];
        #pragma unroll
        for (int s = 0; s < S; ++s) c[s] = pp[s];   // 16 parallel loads
        float best = -1.0f;
        int   bi = 0;
        #pragma unroll
        for (int s = 0; s < S; ++s)
            if (c[s].x > best) { best = c[s].x; bi = __float_as_int(c[s].y); }

        const float2* p2 = (const float2*)(pred + ((size_t)b * An + bi) * PRED_ROW);
        float2 r[7];
        #pragma unroll
        for (int q = 0; q < 7; ++q) r[q] = p2[q];   // 7 parallel loads (56 B row)
        float pcx = r[0].x, pcy = r[0].y, pw = r[1].x, ph = r[1].y, conf = r[2].x;

        const float* bbg = bboxes + ((size_t)b * Gn + g) * 4;
        float b0 = bbg[0], b1 = bbg[1], b2 = bbg[2], b3 = bbg[3];
        float gcx = 0.5f * (b0 + b2), gcy = 0.5f * (b1 + b3);
        float gw = b2 - b0, gh = b3 - b1;

        float dx = pcx - gcx, dy = pcy - gcy, dw = pw - gw, dh = ph - gh;
        float coord = LAMBDA_COORD * (dx * dx + dy * dy + dw * dw + dh * dh);

        float conf_obj = -fmaxf(__logf(conf), -100.0f);

        const float pcls[Cn] = { r[2].y, r[3].x, r[3].y, r[4].x, r[4].y,
                                 r[5].x, r[5].y, r[6].x, r[6].y };
        float clsl = 0.0f;
        #pragma unroll
        for (int c2 = 0; c2 < Cn; ++c2) {
            float pc = pcls[c2];
            float lp = fmaxf(__logf(pc), -100.0f);
            float ln = fmaxf(__logf(1.0f - pc), -100.0f);
            clsl -= (c2 == cls) ? lp : ln;
        }

        float bce0b = -fmaxf(__logf(1.0f - conf), -100.0f);
        float noobj = LAMBDA_NOOBJ * (tot0 - bce0b);

        per_gt = coord + conf_obj + clsl + noobj;
        if (!validf) per_gt = 0.0f;
    }

    float sum = per_gt;
    int   anyv = validf;
    #pragma unroll
    for (int off = 1; off < 64; off <<= 1) {
        sum  += __shfl_xor(sum, off, 64);
        anyv |= __shfl_xor(anyv, off, 64);
    }
    if (g == 0) per_img[b] = anyv ? sum : (LAMBDA_NOOBJ * tot0);
}

__global__ __launch_bounds__(64, 1) void yolo_k3(
    const float* __restrict__ per_img, float* __restrict__ out)
{
    float v = per_img[threadIdx.x];  // Bn == 64 == one wave
    #pragma unroll
    for (int off = 1; off < 64; off <<= 1) v += __shfl_xor(v, off, 64);
    if (threadIdx.x == 0) out[0] = v * (1.0f / (float)Bn);
}

extern "C" void kernel_launch(void* const* d_in, const int* in_sizes, int n_in,
                              void* d_out, int out_size, void* d_ws, size_t ws_size,
                              hipStream_t stream) {
    const float* pred    = (const float*)d_in[0];
    const float* bboxes  = (const float*)d_in[1];
    const int*   classes = (const int*)d_in[2];
    float* out = (float*)d_out;

    char* ws = (char*)d_ws;
    float2* partials = (float2*)ws;
    float*  bcepart  = (float*)(ws + (size_t)Bn * Gn * S * sizeof(float2));
    float*  per_img  = (float*)(ws + (size_t)Bn * Gn * S * sizeof(float2)
                                   + (size_t)Bn * S * sizeof(float));

    yolo_k1<<<dim3(S, Bn), 256, 0, stream>>>(pred, bboxes, partials, bcepart);
    yolo_k2<<<Bn, 64, 0, stream>>>(pred, bboxes, classes, partials, bcepart, per_img);
    yolo_k3<<<1, 64, 0, stream>>>(per_img, out);
}

// Round 6
// 103.429 us; speedup vs baseline: 1.4185x; 1.0383x over previous
//
#include <hip/hip_runtime.h>

#define LAMBDA_COORD 5.0f
#define LAMBDA_NOOBJ 0.5f

constexpr int Bn = 64;       // batch
constexpr int An = 10647;    // anchors
constexpr int Cn = 9;        // classes
constexpr int Gn = 50;       // gt boxes
constexpr int PRED_ROW = 5 + Cn;        // 14 floats per anchor row
constexpr int S  = 16;                  // anchor splits
constexpr int AC = (An + S - 1) / S;    // 666 anchors per split
constexpr int ACP = 768;                // 3*256: exact 3 staging slots/thread
constexpr int GTW = 7;                  // GTs per wave per pass (4*7=28; 2 passes)

// ws layout:
//   partials : Bn*Gn*S float2 (score, idx-as-bits)  = 409600 B
//   bcepart  : Bn*S floats                           = 4096 B
//   per_img  : Bn floats                             = 256 B

// GTW=7: per-wave live set ~ 7*(5 const + 3 accum) = 56 + ~25 temps ≈ 80 VGPR
// -> fits the 128-VGPR cap from (256,4) with slack (GTW=13 needed ~130 and
// spilled the hot arrays to scratch inside the inner loop -> ~2.5x inflation).
__global__ __launch_bounds__(256, 4) void yolo_k1(
    const float* __restrict__ pred,     // [B, A, 14]
    const float* __restrict__ bboxes,   // [B, G, 4]
    float2* __restrict__ partials,      // [B, G, S]
    float* __restrict__ bcepart)        // [B, S]
{
    const int s = blockIdx.x;
    const int b = blockIdx.y;
    const int a0 = s * AC;
    const int n  = min(AC, An - a0);    // 666 (657 for last split)

    __shared__ float4 sbox[ACP];  // x1,y1,x2,y2
    __shared__ float  sap[ACP];   // area_p
    __shared__ float  sred[4];

    const int tid  = threadIdx.x;
    const int wave = tid >> 6;
    const int lane = tid & 63;

    // ---- stage anchors into LDS: branch-free, all 9 loads hoisted ----
    const float* prow = pred + (size_t)b * An * PRED_ROW;
    float2 va[3], vb[3];
    float  vc[3];
    #pragma unroll
    for (int k = 0; k < 3; ++k) {
        int i   = tid + k * 256;                      // < 768 always
        int ild = min(i, n - 1);                      // clamped: load always valid
        const float* p = prow + (size_t)(a0 + ild) * PRED_ROW;
        va[k] = ((const float2*)p)[0];                // cx, cy  (8B-aligned: 56*a)
        vb[k] = ((const float2*)p)[1];                // w, h
        vc[k] = p[4];                                 // conf
    }
    float bce = 0.0f;
    #pragma unroll
    for (int k = 0; k < 3; ++k) {
        int  i     = tid + k * 256;
        bool valid = (i < n);
        float hw = 0.5f * vb[k].x, hh = 0.5f * vb[k].y;
        float x1 = va[k].x - hw, x2 = va[k].x + hw;
        float y1 = va[k].y - hh, y2 = va[k].y + hh;
        // pad sentinel: iw<0 -> inter=0 -> never beats strict-> compare (bn>=0)
        sbox[i] = valid ? make_float4(x1, y1, x2, y2)
                        : make_float4(1e30f, 1e30f, 1e30f, 1e30f);
        sap[i]  = valid ? (x2 - x1) * (y2 - y1) : 0.0f;
        if (valid) bce -= fmaxf(__logf(1.0f - vc[k]), -100.0f);   // bce0
    }
    #pragma unroll
    for (int off = 32; off >= 1; off >>= 1) bce += __shfl_xor(bce, off, 64);
    if (lane == 0) sred[wave] = bce;

    __syncthreads();
    if (tid == 0) bcepart[b * S + s] = sred[0] + sred[1] + sred[2] + sred[3];

    const float* bb = bboxes + (size_t)b * Gn * 4;

    // ---- two passes: pass 0 -> GTs 0..27, pass 1 -> GTs 28..49 ----
    for (int pass = 0; pass < 2; ++pass) {
        const int g0 = pass * 28 + wave * GTW;
        const int ng = min(GTW, Gn - g0);   // 7,7,7,7 then 7,7,7,1

        float gx1[GTW], gy1[GTW], gx2[GTW], gy2[GTW], gc1[GTW];
        #pragma unroll
        for (int j = 0; j < GTW; ++j) {
            int g = (j < ng) ? (g0 + j) : g0;    // pad tail with duplicate GT
            float b0 = bb[g * 4 + 0], b1 = bb[g * 4 + 1];
            float b2 = bb[g * 4 + 2], b3 = bb[g * 4 + 3];
            float gcx = 0.5f * (b0 + b2), gcy = 0.5f * (b1 + b3);
            float gw = b2 - b0, gh = b3 - b1;
            gx1[j] = gcx - gw * 0.5f; gx2[j] = gcx + gw * 0.5f;
            gy1[j] = gcy - gh * 0.5f; gy2[j] = gcy + gh * 0.5f;
            gc1[j] = (gx2[j] - gx1[j]) * (gy2[j] - gy1[j]) + 1e-16f;  // area_g+eps
        }

        float bn[GTW], bd[GTW];
        int   bidx[GTW];
        #pragma unroll
        for (int j = 0; j < GTW; ++j) { bn[j] = 0.0f; bd[j] = 1.0f; bidx[j] = 0; }

        // ---- main scan: branch-free, 7 IoUs per anchor read ----
        for (int base = 0; base < ACP; base += 64) {
            int i = base + lane;
            float4 pb = sbox[i];
            float  ap = sap[i];
            int   idx = a0 + i;
            #pragma unroll
            for (int j = 0; j < GTW; ++j) {
                float iw = fminf(pb.z, gx2[j]) - fmaxf(pb.x, gx1[j]);
                float ih = fminf(pb.w, gy2[j]) - fmaxf(pb.y, gy1[j]);
                iw = fmaxf(iw, 0.0f);
                ih = fmaxf(ih, 0.0f);
                float inter = iw * ih;
                float apc   = ap + gc1[j];
                // argmax of inter/(ap+ag-inter) == argmax of inter/(ap+ag):
                // r -> r/(1+r) monotone; compare fractions by cross-multiply.
                bool take = inter * bd[j] > bn[j] * apc;  // strict >: first max
                bn[j]   = take ? inter : bn[j];
                bd[j]   = take ? apc   : bd[j];
                bidx[j] = take ? idx   : bidx[j];
            }
        }

        // ---- cross-lane argmax per GT, write partial ----
        #pragma unroll
        for (int j = 0; j < GTW; ++j) {
            if (j < ng) {
                float score = bn[j] * __builtin_amdgcn_rcpf(bd[j]); // monotone
                int   idx   = bidx[j];
                #pragma unroll
                for (int off = 1; off < 64; off <<= 1) {
                    float os = __shfl_xor(score, off, 64);
                    int   oi = __shfl_xor(idx, off, 64);
                    if (os > score) { score = os; idx = oi; }
                }
                if (lane == 0)
                    partials[((size_t)b * Gn + g0 + j) * S + s] =
                        make_float2(score, __int_as_float(idx));
            }
        }
    }
}

// k2: one block per image, 64 lanes; lane g owns GT g. __launch_bounds__(64,1)
// removes the VGPR cap so the 16-partial fold + pred row issue as parallel
// loads (single-block variant had VGPR=28 -> serial latency chain, 50 us).
__global__ __launch_bounds__(64, 1) void yolo_k2(
    const float* __restrict__ pred,
    const float* __restrict__ bboxes,
    const int*  __restrict__ classes,   // [B, G]
    const float2* __restrict__ partials,
    const float* __restrict__ bcepart,
    float* __restrict__ per_img)        // [B]
{
    const int b = blockIdx.x;
    const int g = threadIdx.x;

    int cls = (g < Gn) ? classes[b * Gn + g] : -1;

    float tot0 = 0.0f;
    #pragma unroll
    for (int s = 0; s < S; ++s) tot0 += bcepart[b * S + s];  // broadcast loads

    float per_gt = 0.0f;
    int   validf = 0;
    if (g < Gn) {
        validf = (cls != -1) ? 1 : 0;

        const float2* pp = partials + ((size_t)b * Gn + g) * S;
        float2 c[S];
        #pragma unroll
        for (int s = 0; s < S; ++s) c[s] = pp[s];   // 16 parallel loads
        float best = -1.0f;
        int   bi = 0;
        #pragma unroll
        for (int s = 0; s < S; ++s)
            if (c[s].x > best) { best = c[s].x; bi = __float_as_int(c[s].y); }

        const float2* p2 = (const float2*)(pred + ((size_t)b * An + bi) * PRED_ROW);
        float2 r[7];
        #pragma unroll
        for (int q = 0; q < 7; ++q) r[q] = p2[q];   // 7 parallel loads (56 B row)
        float pcx = r[0].x, pcy = r[0].y, pw = r[1].x, ph = r[1].y, conf = r[2].x;

        const float* bbg = bboxes + ((size_t)b * Gn + g) * 4;
        float b0 = bbg[0], b1 = bbg[1], b2 = bbg[2], b3 = bbg[3];
        float gcx = 0.5f * (b0 + b2), gcy = 0.5f * (b1 + b3);
        float gw = b2 - b0, gh = b3 - b1;

        float dx = pcx - gcx, dy = pcy - gcy, dw = pw - gw, dh = ph - gh;
        float coord = LAMBDA_COORD * (dx * dx + dy * dy + dw * dw + dh * dh);

        float conf_obj = -fmaxf(__logf(conf), -100.0f);

        const float pcls[Cn] = { r[2].y, r[3].x, r[3].y, r[4].x, r[4].y,
                                 r[5].x, r[5].y, r[6].x, r[6].y };
        float clsl = 0.0f;
        #pragma unroll
        for (int c2 = 0; c2 < Cn; ++c2) {
            float pc = pcls[c2];
            float lp = fmaxf(__logf(pc), -100.0f);
            float ln = fmaxf(__logf(1.0f - pc), -100.0f);
            clsl -= (c2 == cls) ? lp : ln;
        }

        float bce0b = -fmaxf(__logf(1.0f - conf), -100.0f);
        float noobj = LAMBDA_NOOBJ * (tot0 - bce0b);

        per_gt = coord + conf_obj + clsl + noobj;
        if (!validf) per_gt = 0.0f;
    }

    float sum = per_gt;
    int   anyv = validf;
    #pragma unroll
    for (int off = 1; off < 64; off <<= 1) {
        sum  += __shfl_xor(sum, off, 64);
        anyv |= __shfl_xor(anyv, off, 64);
    }
    if (g == 0) per_img[b] = anyv ? sum : (LAMBDA_NOOBJ * tot0);
}

__global__ __launch_bounds__(64, 1) void yolo_k3(
    const float* __restrict__ per_img, float* __restrict__ out)
{
    float v = per_img[threadIdx.x];  // Bn == 64 == one wave
    #pragma unroll
    for (int off = 1; off < 64; off <<= 1) v += __shfl_xor(v, off, 64);
    if (threadIdx.x == 0) out[0] = v * (1.0f / (float)Bn);
}

extern "C" void kernel_launch(void* const* d_in, const int* in_sizes, int n_in,
                              void* d_out, int out_size, void* d_ws, size_t ws_size,
                              hipStream_t stream) {
    const float* pred    = (const float*)d_in[0];
    const float* bboxes  = (const float*)d_in[1];
    const int*   classes = (const int*)d_in[2];
    float* out = (float*)d_out;

    char* ws = (char*)d_ws;
    float2* partials = (float2*)ws;
    float*  bcepart  = (float*)(ws + (size_t)Bn * Gn * S * sizeof(float2));
    float*  per_img  = (float*)(ws + (size_t)Bn * Gn * S * sizeof(float2)
                                   + (size_t)Bn * S * sizeof(float));

    yolo_k1<<<dim3(S, Bn), 256, 0, stream>>>(pred, bboxes, partials, bcepart);
    yolo_k2<<<Bn, 64, 0, stream>>>(pred, bboxes, classes, partials, bcepart, per_img);
    yolo_k3<<<1, 64, 0, stream>>>(per_img, out);
}